// Round 5
// baseline (126.074 us; speedup 1.0000x reference)
//
#include <hip/hip_runtime.h>
#include <stdint.h>
#include <stddef.h>

typedef __attribute__((ext_vector_type(8))) short short8;
typedef __attribute__((ext_vector_type(4))) short short4v;
typedef __attribute__((ext_vector_type(4))) float f32x4;

typedef const __attribute__((address_space(3))) char* lds_cp;

#define GLDS16(gp, lp)                                                        \
    __builtin_amdgcn_global_load_lds(                                         \
        (const __attribute__((address_space(1))) void*)(gp),                  \
        (__attribute__((address_space(3))) void*)(lp), 16, 0, 0)

// Opaque LDS read: compiler cannot attach alias-driven vmcnt waits (the round-4
// stall theory). Completion is enforced manually via WAIT_LGKM0_PIN.
__device__ __forceinline__ short8 ldsr16(lds_cp p) {
    short8 v;
    asm volatile("ds_read_b128 %0, %1" : "=v"(v) : "v"(p));
    return v;
}

// rule #18: lgkmcnt(0) + sched_barrier(0) so MFMA can't be hoisted past the wait
#define WAIT_LGKM0_PIN()                                                      \
    do {                                                                      \
        asm volatile("s_waitcnt lgkmcnt(0)" ::: "memory");                    \
        __builtin_amdgcn_sched_barrier(0);                                    \
    } while (0)

__device__ __forceinline__ unsigned short f2bf(float f) {
    union { float f; uint32_t u; } v;
    v.f = f;
    uint32_t u = v.u;
    u += 0x7FFFu + ((u >> 16) & 1u);
    return (unsigned short)(u >> 16);
}

// ---------------- weight prep: transpose fp32 [R][C] -> bf16 [C][R] ----------------
__global__ __launch_bounds__(1024) void transpose_to_bf16(
    const float* __restrict__ src, unsigned short* __restrict__ dst, int R, int C)
{
    __shared__ float tile[32][33];
    const int c0 = blockIdx.x * 32, r0 = blockIdx.y * 32;
    const int tx = threadIdx.x, ty = threadIdx.y;
    tile[ty][tx] = src[(size_t)(r0 + ty) * C + (c0 + tx)];
    __syncthreads();
    dst[(size_t)(c0 + ty) * R + (r0 + tx)] = f2bf(tile[tx][ty]);
}

// ---------------- structural features + pack x = [feat | s] as bf16 ----------------
__global__ __launch_bounds__(64) void struct_pack(
    const float* __restrict__ feat0, const float* __restrict__ feat1,
    const float* __restrict__ pts0,  const float* __restrict__ pts1,
    const int* __restrict__ ids0,    const int* __restrict__ ids1,
    unsigned short* __restrict__ xw)
{
    const int m = blockIdx.x;
    const int t = m / 19200;
    const int r = m % 19200;
    const int n = r / 4800;
    const int l = r % 4800;
    const float* feat = t ? feat1 : feat0;
    const float* pts  = (t ? pts1 : pts0) + (size_t)n * (307200 * 3);
    const int*   ids  = (t ? ids1 : ids0) + n * 128;
    const int a = threadIdx.x;  // 0..63

    const int lr = l / 80, lc = l % 80;
    const int p  = (lr * 8) * 640 + lc * 8;
    const float cx = pts[p * 3 + 0], cy = pts[p * 3 + 1], cz = pts[p * 3 + 2];

    const int id0 = ids[a], id1 = ids[a + 64];
    const float d0x = cx - pts[id0 * 3 + 0];
    const float d0y = cy - pts[id0 * 3 + 1];
    const float d0z = cz - pts[id0 * 3 + 2];
    const float d0d = d0x * d0x + d0y * d0y + d0z * d0z;
    const float d1x = cx - pts[id1 * 3 + 0];
    const float d1y = cy - pts[id1 * 3 + 1];
    const float d1z = cz - pts[id1 * 3 + 2];
    const float d1d = d1x * d1x + d1y * d1y + d1z * d1z;

    float p0 = fabsf(d0x) + fabsf(d1x);
    float p1 = fabsf(d0y) + fabsf(d1y);
    float p2 = fabsf(d0z) + fabsf(d1z);
    float p3 = d0d + d1d;
#pragma unroll
    for (int off = 32; off; off >>= 1) {
        p0 += __shfl_xor(p0, off);
        p1 += __shfl_xor(p1, off);
        p2 += __shfl_xor(p2, off);
        p3 += __shfl_xor(p3, off);
    }
    const float i0 = 1.0f / p0, i1 = 1.0f / p1, i2 = 1.0f / p2, i3 = 1.0f / p3;

    unsigned short* xrow = xw + (size_t)m * 768;
    const float* frow = feat + (size_t)(n * 4800 + l) * 256;
    const float4 fv = ((const float4*)frow)[a];
    short4v s4;
    s4.x = (short)f2bf(fv.x); s4.y = (short)f2bf(fv.y);
    s4.z = (short)f2bf(fv.z); s4.w = (short)f2bf(fv.w);
    *(short4v*)(xrow + a * 4) = s4;

    xrow[256 + 0 * 128 + a]      = f2bf(d0x * i0);
    xrow[256 + 0 * 128 + a + 64] = f2bf(d1x * i0);
    xrow[256 + 1 * 128 + a]      = f2bf(d0y * i1);
    xrow[256 + 1 * 128 + a + 64] = f2bf(d1y * i1);
    xrow[256 + 2 * 128 + a]      = f2bf(d0z * i2);
    xrow[256 + 2 * 128 + a + 64] = f2bf(d1z * i2);
    xrow[256 + 3 * 128 + a]      = f2bf(d0d * i3);
    xrow[256 + 3 * 128 + a + 64] = f2bf(d1d * i3);
}

// ---------------- 8-wave 4-phase MFMA GEMM (round-4 structure + opaque LDS reads) ----
// C = act(A @ Bt^T + bias). A:[M,K] bf16, Bt:[N,K] bf16 (pre-transposed weight).
// BM = WRM*MI*16, BN = WRN*NJ*16, BK = 64.
// LDS: A ring-3 (stage t+2 ahead) + B ring-2 (stage t+1 ahead).
// Boundary: s_waitcnt vmcnt(4) (A(t+2)'s 4 loads stay in flight; A(t+1)+B(t+1)
// guaranteed landed) + raw s_barrier -> collective across waves.
// Fragment loads are inline-asm ds_read_b128 (opaque to compiler alias analysis),
// completion enforced by explicit lgkmcnt(0)+sched_barrier(0) per phase.
template <int MI, int NJ, int WRN_LOG, bool RELU, bool OUT_BF16>
__global__ __launch_bounds__(512, 2) void gemm_t(
    const unsigned short* __restrict__ A,
    const unsigned short* __restrict__ Bt,
    const float* __restrict__ bias,
    void* __restrict__ Cout,
    int K, int N, int ntx, int q8, int r8)
{
    constexpr int WRN = 1 << WRN_LOG;
    constexpr int WRM = 8 / WRN;
    constexpr int BM = WRM * MI * 16;
    constexpr int BN = WRN * NJ * 16;
    constexpr int ASLOT = BM * 128;
    constexpr int BSLOT = BN * 128;
    constexpr int ALD = BM / 64;
    constexpr int BLD = BN / 64;
    static_assert(ALD == 4, "vmcnt immediates assume 4 A-loads/wave/tile");

    extern __shared__ char lds[];
    const int nt = K >> 6;

    const int bid = blockIdx.x;
    const int xcd = bid & 7, idx = bid >> 3;
    const int w = (xcd < r8 ? xcd * (q8 + 1) : r8 * (q8 + 1) + (xcd - r8) * q8) + idx;
    const int n0 = (w % ntx) * BN;
    const int m0 = (w / ntx) * BM;

    const int tid = threadIdx.x;
    const int lane = tid & 63;
    const int wv = tid >> 6;
    const int wr = wv >> WRN_LOG;
    const int wc = wv & (WRN - 1);

    // staging (pre-swizzled global source, linear LDS dest)
    const int slr = lane >> 3;
    const int kc  = (lane & 7) ^ slr;
    const unsigned short* gA = A  + (size_t)(m0 + wv * 8 + slr) * K + kc * 8;
    const unsigned short* gB = Bt + (size_t)(n0 + wv * 8 + slr) * K + kc * 8;

    auto stA = [&](int slot, int i, int kt) {
        GLDS16(gA + (size_t)i * 64 * K + kt, lds + slot * ASLOT + (i * 64 + wv * 8) * 128);
    };
    auto stB = [&](int slot, int j, int kt) {
        GLDS16(gB + (size_t)j * 64 * K + kt, lds + 3 * ASLOT + slot * BSLOT + (j * 64 + wv * 8) * 128);
    };

    // read-side addressing (zero-conflict swizzle, measured rounds 2-4)
    const int rsel = lane & 15;
    const int kbh  = lane >> 4;
    const int ck0 = ((kbh) ^ (rsel & 7)) * 16;
    const int ck1 = ((4 + kbh) ^ (rsel & 7)) * 16;
    const int aRowB = (wr * (MI * 16) + rsel) * 128;
    const int bRowB = (wc * (NJ * 16) + rsel) * 128;

    auto LDA = [&](int slot, int mi, int ks) -> short8 {
        return ldsr16((lds_cp)(lds + slot * ASLOT + aRowB + mi * 2048 + (ks ? ck1 : ck0)));
    };
    auto LDB = [&](int slot, int nj, int ks) -> short8 {
        return ldsr16((lds_cp)(lds + 3 * ASLOT + slot * BSLOT + bRowB + nj * 2048 + (ks ? ck1 : ck0)));
    };

    f32x4 acc[MI][NJ] = {};
    short8 aF[MI / 2], bF[NJ];

    // ---- prologue: A(0), B(0), A(1); keep A(1) in flight
    {
#pragma unroll
        for (int i = 0; i < ALD; ++i) stA(0, i, 0);
#pragma unroll
        for (int j = 0; j < BLD; ++j) stB(0, j, 0);
        if (nt > 1) {
#pragma unroll
            for (int i = 0; i < ALD; ++i) stA(1, i, 64);
            asm volatile("s_waitcnt vmcnt(4)" ::: "memory");
        } else {
            asm volatile("s_waitcnt vmcnt(0)" ::: "memory");
        }
        __builtin_amdgcn_s_barrier();
    }

    int cb3 = 0;  // t % 3
    for (int t = 0; t < nt; ++t) {
        const int cb2 = t & 1;
        const int sb2 = cb2 ^ 1;
        int sa3 = cb3 + 2; if (sa3 >= 3) sa3 -= 3;
        const int kt1 = (t + 1) << 6;
        const int kt2 = (t + 2) << 6;
        const bool stb = (t + 1) < nt;
        const bool sta = (t + 2) < nt;

        // ---- phase 0: bF(ks0), aF[lo](ks0); stage B half 0; MFMA lo x all (ks0)
#pragma unroll
        for (int nj = 0; nj < NJ; ++nj) bF[nj] = LDB(cb2, nj, 0);
#pragma unroll
        for (int mi = 0; mi < MI / 2; ++mi) aF[mi] = LDA(cb3, mi, 0);
        if (stb) {
#pragma unroll
            for (int j = 0; j < BLD / 2; ++j) stB(sb2, j, kt1);
        }
        __builtin_amdgcn_s_barrier();
        WAIT_LGKM0_PIN();
        __builtin_amdgcn_s_setprio(1);
#pragma unroll
        for (int mi = 0; mi < MI / 2; ++mi)
#pragma unroll
            for (int nj = 0; nj < NJ; ++nj)
                acc[mi][nj] = __builtin_amdgcn_mfma_f32_16x16x32_bf16(aF[mi], bF[nj], acc[mi][nj], 0, 0, 0);
        __builtin_amdgcn_s_setprio(0);
        __builtin_amdgcn_s_barrier();

        // ---- phase 1: aF[hi](ks0); stage B half 1; MFMA hi x all (ks0)
#pragma unroll
        for (int mi = 0; mi < MI / 2; ++mi) aF[mi] = LDA(cb3, MI / 2 + mi, 0);
        if (stb) {
#pragma unroll
            for (int j = BLD / 2; j < BLD; ++j) stB(sb2, j, kt1);
        }
        __builtin_amdgcn_s_barrier();
        WAIT_LGKM0_PIN();
        __builtin_amdgcn_s_setprio(1);
#pragma unroll
        for (int mi = 0; mi < MI / 2; ++mi)
#pragma unroll
            for (int nj = 0; nj < NJ; ++nj)
                acc[MI / 2 + mi][nj] = __builtin_amdgcn_mfma_f32_16x16x32_bf16(aF[mi], bF[nj], acc[MI / 2 + mi][nj], 0, 0, 0);
        __builtin_amdgcn_s_setprio(0);
        __builtin_amdgcn_s_barrier();

        // ---- phase 2: bF(ks1), aF[lo](ks1); stage A half 0 (t+2); MFMA lo x all (ks1)
#pragma unroll
        for (int nj = 0; nj < NJ; ++nj) bF[nj] = LDB(cb2, nj, 1);
#pragma unroll
        for (int mi = 0; mi < MI / 2; ++mi) aF[mi] = LDA(cb3, mi, 1);
        if (sta) { stA(sa3, 0, kt2); stA(sa3, 1, kt2); }
        __builtin_amdgcn_s_barrier();
        WAIT_LGKM0_PIN();
        __builtin_amdgcn_s_setprio(1);
#pragma unroll
        for (int mi = 0; mi < MI / 2; ++mi)
#pragma unroll
            for (int nj = 0; nj < NJ; ++nj)
                acc[mi][nj] = __builtin_amdgcn_mfma_f32_16x16x32_bf16(aF[mi], bF[nj], acc[mi][nj], 0, 0, 0);
        __builtin_amdgcn_s_setprio(0);
        __builtin_amdgcn_s_barrier();

        // ---- phase 3: aF[hi](ks1); stage A half 1 (t+2); MFMA hi x all (ks1)
#pragma unroll
        for (int mi = 0; mi < MI / 2; ++mi) aF[mi] = LDA(cb3, MI / 2 + mi, 1);
        if (sta) { stA(sa3, 2, kt2); stA(sa3, 3, kt2); }
        __builtin_amdgcn_s_barrier();
        WAIT_LGKM0_PIN();
        __builtin_amdgcn_s_setprio(1);
#pragma unroll
        for (int mi = 0; mi < MI / 2; ++mi)
#pragma unroll
            for (int nj = 0; nj < NJ; ++nj)
                acc[MI / 2 + mi][nj] = __builtin_amdgcn_mfma_f32_16x16x32_bf16(aF[mi], bF[nj], acc[MI / 2 + mi][nj], 0, 0, 0);
        __builtin_amdgcn_s_setprio(0);

        // ---- tile boundary: counted vmcnt, collective via barrier
        if (t + 1 < nt) {
            if (t + 2 < nt) asm volatile("s_waitcnt vmcnt(4)" ::: "memory");
            else            asm volatile("s_waitcnt vmcnt(0)" ::: "memory");
            __builtin_amdgcn_s_barrier();
        }
        cb3 = (cb3 + 1 == 3) ? 0 : cb3 + 1;
    }

    // epilogue: C/D layout (m89): col = lane&15, row = (lane>>4)*4 + reg
    const int crow = (lane >> 4) * 4;
    const int ccol = lane & 15;
#pragma unroll
    for (int nj = 0; nj < NJ; ++nj) {
        const int col = n0 + wc * (NJ * 16) + nj * 16 + ccol;
        const float bv = bias[col];
#pragma unroll
        for (int mi = 0; mi < MI; ++mi) {
#pragma unroll
            for (int rg = 0; rg < 4; ++rg) {
                const int row = m0 + wr * (MI * 16) + mi * 16 + crow + rg;
                float v = acc[mi][nj][rg] + bv;
                if (RELU) v = fmaxf(v, 0.0f);
                if (OUT_BF16) {
                    ((unsigned short*)Cout)[(size_t)row * N + col] = f2bf(v);
                } else {
                    ((float*)Cout)[(size_t)row * N + col] = v;
                }
            }
        }
    }
}

extern "C" void kernel_launch(void* const* d_in, const int* in_sizes, int n_in,
                              void* d_out, int out_size, void* d_ws, size_t ws_size,
                              hipStream_t stream) {
    const float* feat0 = (const float*)d_in[0];
    const float* feat1 = (const float*)d_in[1];
    const float* pts0  = (const float*)d_in[2];
    const float* pts1  = (const float*)d_in[3];
    const int*   ids0  = (const int*)d_in[4];
    const int*   ids1  = (const int*)d_in[5];
    const float* W1    = (const float*)d_in[6];
    const float* b1    = (const float*)d_in[7];
    const float* W2    = (const float*)d_in[8];
    const float* b2    = (const float*)d_in[9];
    float* out = (float*)d_out;

    char* ws = (char*)d_ws;
    unsigned short* xw  = (unsigned short*)(ws);
    unsigned short* h   = (unsigned short*)(ws + 58982400);
    unsigned short* w1t = (unsigned short*)(ws + 117964800);
    unsigned short* w2t = (unsigned short*)(ws + 119144448);

    // GEMM1: 256x256 tile, waves 2Mx4N (wave tile 128x64): MI=8, NJ=4, WRN_LOG=2
    const int LDS1 = 3 * 32768 + 2 * 32768;
    // GEMM2: 256x128 tile, waves 4Mx2N (wave tile 64x64): MI=4, NJ=4, WRN_LOG=1
    const int LDS2 = 3 * 32768 + 2 * 16384;
    (void)hipFuncSetAttribute((const void*)&gemm_t<8, 4, 2, true, true>,
                              hipFuncAttributeMaxDynamicSharedMemorySize, LDS1);
    (void)hipFuncSetAttribute((const void*)&gemm_t<4, 4, 1, false, false>,
                              hipFuncAttributeMaxDynamicSharedMemorySize, LDS2);

    dim3 tb(32, 32);
    transpose_to_bf16<<<dim3(768 / 32, 768 / 32), tb, 0, stream>>>(W1, w1t, 768, 768);
    transpose_to_bf16<<<dim3(256 / 32, 768 / 32), tb, 0, stream>>>(W2, w2t, 768, 256);

    struct_pack<<<38400, 64, 0, stream>>>(feat0, feat1, pts0, pts1, ids0, ids1, xw);

    // GEMM1: h = relu(x @ W1 + b1)  M=38400, N=768 -> tiles 150m x 3n = 450 wg (q=56, r=2)
    gemm_t<8, 4, 2, true, true><<<450, 512, LDS1, stream>>>(xw, w1t, b1, (void*)h, 768, 768, 3, 56, 2);
    // GEMM2: out = h @ W2 + b2      M=38400, N=256 -> tiles 150m x 2n = 300 wg (q=37, r=4)
    gemm_t<4, 4, 1, false, false><<<300, 512, LDS2, stream>>>(h, w2t, b2, (void*)out, 768, 256, 2, 37, 4);
}

// Round 6
// 116.881 us; speedup vs baseline: 1.0786x; 1.0786x over previous
//
#include <hip/hip_runtime.h>
#include <stdint.h>
#include <stddef.h>

typedef __attribute__((ext_vector_type(8))) short short8;
typedef __attribute__((ext_vector_type(4))) short short4v;
typedef __attribute__((ext_vector_type(4))) float f32x4;

typedef const __attribute__((address_space(3))) char* lds_cp;

#define GLDS16(gp, lp)                                                        \
    __builtin_amdgcn_global_load_lds(                                         \
        (const __attribute__((address_space(1))) void*)(gp),                  \
        (__attribute__((address_space(3))) void*)(lp), 16, 0, 0)

// Opaque LDS read: no compiler-inserted waits; completion via counted lgkmcnt.
__device__ __forceinline__ short8 ldsr16(lds_cp p) {
    short8 v;
    asm volatile("ds_read_b128 %0, %1" : "=v"(v) : "v"(p));
    return v;
}

// rule #18: counted lgkm wait + sched_barrier(0) so MFMA can't hoist above it
template <int N>
__device__ __forceinline__ void wait_lgkm() {
    static_assert(N == 0 || N == 2 || N == 4 || N == 8, "unsupported count");
    if constexpr (N == 0) asm volatile("s_waitcnt lgkmcnt(0)" ::: "memory");
    else if constexpr (N == 2) asm volatile("s_waitcnt lgkmcnt(2)" ::: "memory");
    else if constexpr (N == 4) asm volatile("s_waitcnt lgkmcnt(4)" ::: "memory");
    else if constexpr (N == 8) asm volatile("s_waitcnt lgkmcnt(8)" ::: "memory");
    __builtin_amdgcn_sched_barrier(0);
}

__device__ __forceinline__ unsigned short f2bf(float f) {
    union { float f; uint32_t u; } v;
    v.f = f;
    uint32_t u = v.u;
    u += 0x7FFFu + ((u >> 16) & 1u);
    return (unsigned short)(u >> 16);
}

// ---------------- weight prep: transpose fp32 [R][C] -> bf16 [C][R] ----------------
__global__ __launch_bounds__(1024) void transpose_to_bf16(
    const float* __restrict__ src, unsigned short* __restrict__ dst, int R, int C)
{
    __shared__ float tile[32][33];
    const int c0 = blockIdx.x * 32, r0 = blockIdx.y * 32;
    const int tx = threadIdx.x, ty = threadIdx.y;
    tile[ty][tx] = src[(size_t)(r0 + ty) * C + (c0 + tx)];
    __syncthreads();
    dst[(size_t)(c0 + ty) * R + (r0 + tx)] = f2bf(tile[tx][ty]);
}

// ---------------- structural features + pack x = [feat | s] as bf16 ----------------
__global__ __launch_bounds__(64) void struct_pack(
    const float* __restrict__ feat0, const float* __restrict__ feat1,
    const float* __restrict__ pts0,  const float* __restrict__ pts1,
    const int* __restrict__ ids0,    const int* __restrict__ ids1,
    unsigned short* __restrict__ xw)
{
    const int m = blockIdx.x;
    const int t = m / 19200;
    const int r = m % 19200;
    const int n = r / 4800;
    const int l = r % 4800;
    const float* feat = t ? feat1 : feat0;
    const float* pts  = (t ? pts1 : pts0) + (size_t)n * (307200 * 3);
    const int*   ids  = (t ? ids1 : ids0) + n * 128;
    const int a = threadIdx.x;  // 0..63

    const int lr = l / 80, lc = l % 80;
    const int p  = (lr * 8) * 640 + lc * 8;
    const float cx = pts[p * 3 + 0], cy = pts[p * 3 + 1], cz = pts[p * 3 + 2];

    const int id0 = ids[a], id1 = ids[a + 64];
    const float d0x = cx - pts[id0 * 3 + 0];
    const float d0y = cy - pts[id0 * 3 + 1];
    const float d0z = cz - pts[id0 * 3 + 2];
    const float d0d = d0x * d0x + d0y * d0y + d0z * d0z;
    const float d1x = cx - pts[id1 * 3 + 0];
    const float d1y = cy - pts[id1 * 3 + 1];
    const float d1z = cz - pts[id1 * 3 + 2];
    const float d1d = d1x * d1x + d1y * d1y + d1z * d1z;

    float p0 = fabsf(d0x) + fabsf(d1x);
    float p1 = fabsf(d0y) + fabsf(d1y);
    float p2 = fabsf(d0z) + fabsf(d1z);
    float p3 = d0d + d1d;
#pragma unroll
    for (int off = 32; off; off >>= 1) {
        p0 += __shfl_xor(p0, off);
        p1 += __shfl_xor(p1, off);
        p2 += __shfl_xor(p2, off);
        p3 += __shfl_xor(p3, off);
    }
    const float i0 = 1.0f / p0, i1 = 1.0f / p1, i2 = 1.0f / p2, i3 = 1.0f / p3;

    unsigned short* xrow = xw + (size_t)m * 768;
    const float* frow = feat + (size_t)(n * 4800 + l) * 256;
    const float4 fv = ((const float4*)frow)[a];
    short4v s4;
    s4.x = (short)f2bf(fv.x); s4.y = (short)f2bf(fv.y);
    s4.z = (short)f2bf(fv.z); s4.w = (short)f2bf(fv.w);
    *(short4v*)(xrow + a * 4) = s4;

    xrow[256 + 0 * 128 + a]      = f2bf(d0x * i0);
    xrow[256 + 0 * 128 + a + 64] = f2bf(d1x * i0);
    xrow[256 + 1 * 128 + a]      = f2bf(d0y * i1);
    xrow[256 + 1 * 128 + a + 64] = f2bf(d1y * i1);
    xrow[256 + 2 * 128 + a]      = f2bf(d0z * i2);
    xrow[256 + 2 * 128 + a + 64] = f2bf(d1z * i2);
    xrow[256 + 3 * 128 + a]      = f2bf(d0d * i3);
    xrow[256 + 3 * 128 + a + 64] = f2bf(d1d * i3);
}

// ---------------- 8-wave barrier-free-intra-tile MFMA GEMM ----------------
// C = act(A @ Bt^T + bias). A:[M,K] bf16, Bt:[N,K] bf16 (pre-transposed weight).
// BM = WRM*MI*16, BN = WRN*NJ*16, BK = 64. LDS: A ring-3 (stage t+2) + B ring-2 (stage t+1).
// NO intra-tile barriers: each wave issues ds_reads in 4 groups, consumes via counted
// lgkmcnt waits (DS completes in order; max 12 in flight < 15-count limit). Waves slip
// against each other so LDS-pipe and matrix-pipe overlap across the CU.
// One boundary per tile: s_waitcnt vmcnt(4) (A(t+2)'s loads stay in flight; A(t+1)+B(t+1)
// proven landed) + raw s_barrier. Zero-conflict LDS swizzle (measured rounds 2-5).
template <int MI, int NJ, int WRN_LOG, bool RELU, bool OUT_BF16>
__global__ __launch_bounds__(512, 2) void gemm_t(
    const unsigned short* __restrict__ A,
    const unsigned short* __restrict__ Bt,
    const float* __restrict__ bias,
    void* __restrict__ Cout,
    int K, int N, int ntx, int q8, int r8)
{
    constexpr int WRN = 1 << WRN_LOG;
    constexpr int WRM = 8 / WRN;
    constexpr int BM = WRM * MI * 16;
    constexpr int BN = WRN * NJ * 16;
    constexpr int ASLOT = BM * 128;
    constexpr int BSLOT = BN * 128;
    constexpr int ALD = BM / 64;
    constexpr int BLD = BN / 64;
    static_assert(ALD == 4, "vmcnt immediates assume 4 A-loads/wave/tile");
    static_assert(MI + NJ <= 13, "lgkm in-flight cap");

    extern __shared__ char lds[];
    const int nt = K >> 6;

    const int bid = blockIdx.x;
    const int xcd = bid & 7, idx = bid >> 3;
    const int w = (xcd < r8 ? xcd * (q8 + 1) : r8 * (q8 + 1) + (xcd - r8) * q8) + idx;
    const int n0 = (w % ntx) * BN;
    const int m0 = (w / ntx) * BM;

    const int tid = threadIdx.x;
    const int lane = tid & 63;
    const int wv = tid >> 6;
    const int wr = wv >> WRN_LOG;
    const int wc = wv & (WRN - 1);

    // staging (pre-swizzled global source, linear LDS dest)
    const int slr = lane >> 3;
    const int kc  = (lane & 7) ^ slr;
    const unsigned short* gA = A  + (size_t)(m0 + wv * 8 + slr) * K + kc * 8;
    const unsigned short* gB = Bt + (size_t)(n0 + wv * 8 + slr) * K + kc * 8;

    auto stA = [&](int slot, int i, int kt) {
        GLDS16(gA + (size_t)i * 64 * K + kt, lds + slot * ASLOT + (i * 64 + wv * 8) * 128);
    };
    auto stB = [&](int slot, int j, int kt) {
        GLDS16(gB + (size_t)j * 64 * K + kt, lds + 3 * ASLOT + slot * BSLOT + (j * 64 + wv * 8) * 128);
    };

    // read-side addressing (zero-conflict swizzle)
    const int rsel = lane & 15;
    const int kbh  = lane >> 4;
    const int ck0 = ((kbh) ^ (rsel & 7)) * 16;
    const int ck1 = ((4 + kbh) ^ (rsel & 7)) * 16;
    const int aRowB = (wr * (MI * 16) + rsel) * 128;
    const int bRowB = (wc * (NJ * 16) + rsel) * 128;

    auto LDA = [&](int slot, int mi, int ks) -> short8 {
        return ldsr16((lds_cp)(lds + slot * ASLOT + aRowB + mi * 2048 + (ks ? ck1 : ck0)));
    };
    auto LDB = [&](int slot, int nj, int ks) -> short8 {
        return ldsr16((lds_cp)(lds + 3 * ASLOT + slot * BSLOT + bRowB + nj * 2048 + (ks ? ck1 : ck0)));
    };

    f32x4 acc[MI][NJ] = {};
    short8 aL[MI / 2], aH[MI / 2], aL1[MI / 2], aH1[MI / 2], bF0[NJ], bF1[NJ];

    // ---- prologue: A(0), B(0), A(1); keep A(1) in flight
    {
#pragma unroll
        for (int i = 0; i < ALD; ++i) stA(0, i, 0);
#pragma unroll
        for (int j = 0; j < BLD; ++j) stB(0, j, 0);
        if (nt > 1) {
#pragma unroll
            for (int i = 0; i < ALD; ++i) stA(1, i, 64);
            asm volatile("s_waitcnt vmcnt(4)" ::: "memory");
        } else {
            asm volatile("s_waitcnt vmcnt(0)" ::: "memory");
        }
        __builtin_amdgcn_s_barrier();
    }

    int cb3 = 0;  // t % 3
    for (int t = 0; t < nt; ++t) {
        const int cb2 = t & 1;
        const int sb2 = cb2 ^ 1;
        int sa3 = cb3 + 2; if (sa3 >= 3) sa3 -= 3;
        const int kt1 = (t + 1) << 6;
        const int kt2 = (t + 2) << 6;
        const bool stb = (t + 1) < nt;
        const bool sta = (t + 2) < nt;

        // ---- G1: B(ks0) + A-lo(ks0); G2: A-hi(ks0)
#pragma unroll
        for (int nj = 0; nj < NJ; ++nj) bF0[nj] = LDB(cb2, nj, 0);
#pragma unroll
        for (int mi = 0; mi < MI / 2; ++mi) aL[mi] = LDA(cb3, mi, 0);
#pragma unroll
        for (int mi = 0; mi < MI / 2; ++mi) aH[mi] = LDA(cb3, MI / 2 + mi, 0);

        // ---- c1: lo x all (ks0) once G1 landed (G2 may still be in flight)
        wait_lgkm<MI / 2>();
        __builtin_amdgcn_s_setprio(1);
#pragma unroll
        for (int mi = 0; mi < MI / 2; ++mi)
#pragma unroll
            for (int nj = 0; nj < NJ; ++nj)
                acc[mi][nj] = __builtin_amdgcn_mfma_f32_16x16x32_bf16(aL[mi], bF0[nj], acc[mi][nj], 0, 0, 0);
        __builtin_amdgcn_s_setprio(0);

        // ---- G3: B(ks1); stage B(t+1)
#pragma unroll
        for (int nj = 0; nj < NJ; ++nj) bF1[nj] = LDB(cb2, nj, 1);
        if (stb) {
#pragma unroll
            for (int j = 0; j < BLD; ++j) stB(sb2, j, kt1);
        }

        // ---- c2: hi x all (ks0) once G2 landed
        wait_lgkm<NJ>();
        __builtin_amdgcn_s_setprio(1);
#pragma unroll
        for (int mi = 0; mi < MI / 2; ++mi)
#pragma unroll
            for (int nj = 0; nj < NJ; ++nj)
                acc[MI / 2 + mi][nj] = __builtin_amdgcn_mfma_f32_16x16x32_bf16(aH[mi], bF0[nj], acc[MI / 2 + mi][nj], 0, 0, 0);
        __builtin_amdgcn_s_setprio(0);

        // ---- G4: A-lo(ks1) + A-hi(ks1); stage A(t+2)
#pragma unroll
        for (int mi = 0; mi < MI / 2; ++mi) aL1[mi] = LDA(cb3, mi, 1);
#pragma unroll
        for (int mi = 0; mi < MI / 2; ++mi) aH1[mi] = LDA(cb3, MI / 2 + mi, 1);
        if (sta) {
            stA(sa3, 0, kt2); stA(sa3, 1, kt2); stA(sa3, 2, kt2); stA(sa3, 3, kt2);
        }

        // ---- c3: lo x all (ks1) once B(ks1)+A-lo(ks1) landed
        wait_lgkm<MI / 2>();
        __builtin_amdgcn_s_setprio(1);
#pragma unroll
        for (int mi = 0; mi < MI / 2; ++mi)
#pragma unroll
            for (int nj = 0; nj < NJ; ++nj)
                acc[mi][nj] = __builtin_amdgcn_mfma_f32_16x16x32_bf16(aL1[mi], bF1[nj], acc[mi][nj], 0, 0, 0);
        __builtin_amdgcn_s_setprio(0);

        // ---- c4: hi x all (ks1) once everything landed
        wait_lgkm<0>();
        __builtin_amdgcn_s_setprio(1);
#pragma unroll
        for (int mi = 0; mi < MI / 2; ++mi)
#pragma unroll
            for (int nj = 0; nj < NJ; ++nj)
                acc[MI / 2 + mi][nj] = __builtin_amdgcn_mfma_f32_16x16x32_bf16(aH1[mi], bF1[nj], acc[MI / 2 + mi][nj], 0, 0, 0);
        __builtin_amdgcn_s_setprio(0);

        // ---- tile boundary: counted vmcnt (A(t+2) stays in flight), collective barrier
        if (t + 1 < nt) {
            if (sta) asm volatile("s_waitcnt vmcnt(4)" ::: "memory");
            else     asm volatile("s_waitcnt vmcnt(0)" ::: "memory");
            __builtin_amdgcn_s_barrier();
        }
        cb3 = (cb3 + 1 == 3) ? 0 : cb3 + 1;
    }

    // epilogue: C/D layout (m89): col = lane&15, row = (lane>>4)*4 + reg
    const int crow = (lane >> 4) * 4;
    const int ccol = lane & 15;
#pragma unroll
    for (int nj = 0; nj < NJ; ++nj) {
        const int col = n0 + wc * (NJ * 16) + nj * 16 + ccol;
        const float bv = bias[col];
#pragma unroll
        for (int mi = 0; mi < MI; ++mi) {
#pragma unroll
            for (int rg = 0; rg < 4; ++rg) {
                const int row = m0 + wr * (MI * 16) + mi * 16 + crow + rg;
                float v = acc[mi][nj][rg] + bv;
                if (RELU) v = fmaxf(v, 0.0f);
                if (OUT_BF16) {
                    ((unsigned short*)Cout)[(size_t)row * N + col] = f2bf(v);
                } else {
                    ((float*)Cout)[(size_t)row * N + col] = v;
                }
            }
        }
    }
}

extern "C" void kernel_launch(void* const* d_in, const int* in_sizes, int n_in,
                              void* d_out, int out_size, void* d_ws, size_t ws_size,
                              hipStream_t stream) {
    const float* feat0 = (const float*)d_in[0];
    const float* feat1 = (const float*)d_in[1];
    const float* pts0  = (const float*)d_in[2];
    const float* pts1  = (const float*)d_in[3];
    const int*   ids0  = (const int*)d_in[4];
    const int*   ids1  = (const int*)d_in[5];
    const float* W1    = (const float*)d_in[6];
    const float* b1    = (const float*)d_in[7];
    const float* W2    = (const float*)d_in[8];
    const float* b2    = (const float*)d_in[9];
    float* out = (float*)d_out;

    char* ws = (char*)d_ws;
    unsigned short* xw  = (unsigned short*)(ws);
    unsigned short* h   = (unsigned short*)(ws + 58982400);
    unsigned short* w1t = (unsigned short*)(ws + 117964800);
    unsigned short* w2t = (unsigned short*)(ws + 119144448);

    // GEMM1: 256x256 tile, waves 2Mx4N (wave tile 128x64): MI=8, NJ=4, WRN_LOG=2
    const int LDS1 = 3 * 32768 + 2 * 32768;
    // GEMM2: 256x128 tile, waves 4Mx2N (wave tile 64x64): MI=4, NJ=4, WRN_LOG=1
    const int LDS2 = 3 * 32768 + 2 * 16384;
    (void)hipFuncSetAttribute((const void*)&gemm_t<8, 4, 2, true, true>,
                              hipFuncAttributeMaxDynamicSharedMemorySize, LDS1);
    (void)hipFuncSetAttribute((const void*)&gemm_t<4, 4, 1, false, false>,
                              hipFuncAttributeMaxDynamicSharedMemorySize, LDS2);

    dim3 tb(32, 32);
    transpose_to_bf16<<<dim3(768 / 32, 768 / 32), tb, 0, stream>>>(W1, w1t, 768, 768);
    transpose_to_bf16<<<dim3(256 / 32, 768 / 32), tb, 0, stream>>>(W2, w2t, 768, 256);

    struct_pack<<<38400, 64, 0, stream>>>(feat0, feat1, pts0, pts1, ids0, ids1, xw);

    // GEMM1: h = relu(x @ W1 + b1)  M=38400, N=768 -> tiles 150m x 3n = 450 wg (q=56, r=2)
    gemm_t<8, 4, 2, true, true><<<450, 512, LDS1, stream>>>(xw, w1t, b1, (void*)h, 768, 768, 3, 56, 2);
    // GEMM2: out = h @ W2 + b2      M=38400, N=256 -> tiles 150m x 2n = 300 wg (q=37, r=4)
    gemm_t<4, 4, 1, false, false><<<300, 512, LDS2, stream>>>(h, w2t, b2, (void*)out, 768, 256, 2, 37, 4);
}

// Round 7
// 115.974 us; speedup vs baseline: 1.0871x; 1.0078x over previous
//
#include <hip/hip_runtime.h>
#include <stdint.h>
#include <stddef.h>

typedef __attribute__((ext_vector_type(8))) short short8;
typedef __attribute__((ext_vector_type(4))) short short4v;
typedef __attribute__((ext_vector_type(4))) float f32x4;

typedef const __attribute__((address_space(3))) char* lds_cp;

#define GLDS16(gp, lp)                                                        \
    __builtin_amdgcn_global_load_lds(                                         \
        (const __attribute__((address_space(1))) void*)(gp),                  \
        (__attribute__((address_space(3))) void*)(lp), 16, 0, 0)

// Opaque LDS read: no compiler-inserted waits; completion via counted lgkmcnt.
__device__ __forceinline__ short8 ldsr16(lds_cp p) {
    short8 v;
    asm volatile("ds_read_b128 %0, %1" : "=v"(v) : "v"(p));
    return v;
}

// rule #18: counted lgkm wait + sched_barrier(0) so MFMA can't hoist above it
template <int N>
__device__ __forceinline__ void wait_lgkm() {
    static_assert(N == 0 || N == 4, "unsupported count");
    if constexpr (N == 0) asm volatile("s_waitcnt lgkmcnt(0)" ::: "memory");
    else asm volatile("s_waitcnt lgkmcnt(4)" ::: "memory");
    __builtin_amdgcn_sched_barrier(0);
}

__device__ __forceinline__ unsigned short f2bf(float f) {
    union { float f; uint32_t u; } v;
    v.f = f;
    uint32_t u = v.u;
    u += 0x7FFFu + ((u >> 16) & 1u);
    return (unsigned short)(u >> 16);
}

// ---------------- weight prep: transpose fp32 [R][C] -> bf16 [C][R] ----------------
__global__ __launch_bounds__(1024) void transpose_to_bf16(
    const float* __restrict__ src, unsigned short* __restrict__ dst, int R, int C)
{
    __shared__ float tile[32][33];
    const int c0 = blockIdx.x * 32, r0 = blockIdx.y * 32;
    const int tx = threadIdx.x, ty = threadIdx.y;
    tile[ty][tx] = src[(size_t)(r0 + ty) * C + (c0 + tx)];
    __syncthreads();
    dst[(size_t)(c0 + ty) * R + (r0 + tx)] = f2bf(tile[tx][ty]);
}

// ---------------- structural features + pack x = [feat | s] as bf16 ----------------
__global__ __launch_bounds__(64) void struct_pack(
    const float* __restrict__ feat0, const float* __restrict__ feat1,
    const float* __restrict__ pts0,  const float* __restrict__ pts1,
    const int* __restrict__ ids0,    const int* __restrict__ ids1,
    unsigned short* __restrict__ xw)
{
    const int m = blockIdx.x;
    const int t = m / 19200;
    const int r = m % 19200;
    const int n = r / 4800;
    const int l = r % 4800;
    const float* feat = t ? feat1 : feat0;
    const float* pts  = (t ? pts1 : pts0) + (size_t)n * (307200 * 3);
    const int*   ids  = (t ? ids1 : ids0) + n * 128;
    const int a = threadIdx.x;  // 0..63

    const int lr = l / 80, lc = l % 80;
    const int p  = (lr * 8) * 640 + lc * 8;
    const float cx = pts[p * 3 + 0], cy = pts[p * 3 + 1], cz = pts[p * 3 + 2];

    const int id0 = ids[a], id1 = ids[a + 64];
    const float d0x = cx - pts[id0 * 3 + 0];
    const float d0y = cy - pts[id0 * 3 + 1];
    const float d0z = cz - pts[id0 * 3 + 2];
    const float d0d = d0x * d0x + d0y * d0y + d0z * d0z;
    const float d1x = cx - pts[id1 * 3 + 0];
    const float d1y = cy - pts[id1 * 3 + 1];
    const float d1z = cz - pts[id1 * 3 + 2];
    const float d1d = d1x * d1x + d1y * d1y + d1z * d1z;

    float p0 = fabsf(d0x) + fabsf(d1x);
    float p1 = fabsf(d0y) + fabsf(d1y);
    float p2 = fabsf(d0z) + fabsf(d1z);
    float p3 = d0d + d1d;
#pragma unroll
    for (int off = 32; off; off >>= 1) {
        p0 += __shfl_xor(p0, off);
        p1 += __shfl_xor(p1, off);
        p2 += __shfl_xor(p2, off);
        p3 += __shfl_xor(p3, off);
    }
    const float i0 = 1.0f / p0, i1 = 1.0f / p1, i2 = 1.0f / p2, i3 = 1.0f / p3;

    unsigned short* xrow = xw + (size_t)m * 768;
    const float* frow = feat + (size_t)(n * 4800 + l) * 256;
    const float4 fv = ((const float4*)frow)[a];
    short4v s4;
    s4.x = (short)f2bf(fv.x); s4.y = (short)f2bf(fv.y);
    s4.z = (short)f2bf(fv.z); s4.w = (short)f2bf(fv.w);
    *(short4v*)(xrow + a * 4) = s4;

    xrow[256 + 0 * 128 + a]      = f2bf(d0x * i0);
    xrow[256 + 0 * 128 + a + 64] = f2bf(d1x * i0);
    xrow[256 + 1 * 128 + a]      = f2bf(d0y * i1);
    xrow[256 + 1 * 128 + a + 64] = f2bf(d1y * i1);
    xrow[256 + 2 * 128 + a]      = f2bf(d0z * i2);
    xrow[256 + 2 * 128 + a + 64] = f2bf(d1z * i2);
    xrow[256 + 3 * 128 + a]      = f2bf(d0d * i3);
    xrow[256 + 3 * 128 + a + 64] = f2bf(d1d * i3);
}

// ---------------- 4-wave 2-blocks/CU MFMA GEMM ----------------
// C = act(A @ Bt^T + bias). A:[M,K] bf16, Bt:[N,K] bf16 (pre-transposed weight).
// BM=256, BN=128, BK=32. 4 waves (2M x 2N), wave tile 128x64 (8x4 frags 16x16x32).
// LDS: A ring-3 (16KB, stage t+2) + B ring-2 (8KB, stage t+1) = 64KB -> 2 blocks/CU.
// Two independent blocks per CU give cross-block MFMA/LDS/barrier overlap that a single
// barrier-locked block cannot (rounds 3-6 plateau). Counted waits throughout:
// boundary s_waitcnt vmcnt(4) + s_barrier; intra-tile lgkmcnt(4)/(0) before MFMA clusters.
// BK=32 rows are 64B; conflict swizzle: phys 16B-chunk = q ^ ((row>>1)&3) (2-way = free),
// inverse pre-applied on the staging GLOBAL source so LDS dest stays linear (m173).
template <bool RELU, bool OUT_BF16>
__global__ __launch_bounds__(256, 2) void gemm_t(
    const unsigned short* __restrict__ A,
    const unsigned short* __restrict__ Bt,
    const float* __restrict__ bias,
    void* __restrict__ Cout,
    int K, int N, int ntx, int q8, int r8)
{
    constexpr int ASLOT = 256 * 64;   // 16 KB
    constexpr int BSLOT = 128 * 64;   // 8 KB
    extern __shared__ char lds[];
    char* ldsB = lds + 3 * ASLOT;
    const int nt = K >> 5;

    const int bid = blockIdx.x;
    const int xcd = bid & 7, idx = bid >> 3;
    const int w = (xcd < r8 ? xcd * (q8 + 1) : r8 * (q8 + 1) + (xcd - r8) * q8) + idx;
    const int n0 = (w % ntx) * 128;
    const int m0 = (w / ntx) * 256;

    const int tid = threadIdx.x;
    const int lane = tid & 63;
    const int wv = tid >> 6;       // 0..3
    const int wr = wv >> 1;        // 0..1 (M)
    const int wc = wv & 1;         // 0..1 (N)

    // staging: per instr, 64 lanes x 16B = 16 rows x 64B (one 16-row chunk of [*][32k]).
    // dest is wave-uniform base (HW adds lane*16). Global source carries the inverse
    // read swizzle: dest row-in-16 = l>>2, dest chunk = l&3 -> logical chunk = (l&3)^((l>>3)&3).
    const int lrow = lane >> 2;
    const int lchk = (lane & 3) ^ ((lane >> 3) & 3);
    const unsigned short* gA = A  + (size_t)(m0 + wv * 64 + lrow) * K + lchk * 8;
    const unsigned short* gB = Bt + (size_t)(n0 + wv * 32 + lrow) * K + lchk * 8;

    auto stA = [&](int slot, int i, int kt) {
        GLDS16(gA + (size_t)i * 16 * K + kt, lds + slot * ASLOT + (wv * 4 + i) * 1024);
    };
    auto stB = [&](int slot, int j, int kt) {
        GLDS16(gB + (size_t)j * 16 * K + kt, ldsB + slot * BSLOT + (wv * 2 + j) * 1024);
    };

    // fragment reads: lane (R=lane&15 row, q=lane>>4 k-chunk); phys chunk = q^((R>>1)&3)
    const int R = lane & 15;
    const int q = lane >> 4;
    const int ck = (q ^ ((R >> 1) & 3)) * 16;
    const int aOff = (wr * 128 + R) * 64 + ck;
    const int bOff = (wc * 64 + R) * 64 + ck;

    auto LDA = [&](int slot, int mi) -> short8 {
        return ldsr16((lds_cp)(lds + slot * ASLOT + aOff + mi * 1024));
    };
    auto LDB = [&](int slot, int nj) -> short8 {
        return ldsr16((lds_cp)(ldsB + slot * BSLOT + bOff + nj * 1024));
    };

    f32x4 acc[8][4] = {};
    short8 aF[8], bF[4];

    // ---- prologue: A(0) 4, B(0) 2, A(1) 4; keep A(1) in flight
    {
        stA(0, 0, 0); stA(0, 1, 0); stA(0, 2, 0); stA(0, 3, 0);
        stB(0, 0, 0); stB(0, 1, 0);
        if (nt > 1) {
            stA(1, 0, 32); stA(1, 1, 32); stA(1, 2, 32); stA(1, 3, 32);
            asm volatile("s_waitcnt vmcnt(4)" ::: "memory");
        } else {
            asm volatile("s_waitcnt vmcnt(0)" ::: "memory");
        }
        __builtin_amdgcn_s_barrier();
    }

    int cb3 = 0;  // t % 3
    for (int t = 0; t < nt; ++t) {
        const int cb2 = t & 1;
        const int sb2 = cb2 ^ 1;
        int sa3 = cb3 + 2; if (sa3 >= 3) sa3 -= 3;
        const int kt1 = (t + 1) << 5;
        const int kt2 = (t + 2) << 5;
        const bool stb = (t + 1) < nt;
        const bool sta = (t + 2) < nt;

        // ---- G1: B frags (4) + A-lo frags (4); stage B(t+1)
        bF[0] = LDB(cb2, 0); bF[1] = LDB(cb2, 1); bF[2] = LDB(cb2, 2); bF[3] = LDB(cb2, 3);
        aF[0] = LDA(cb3, 0); aF[1] = LDA(cb3, 1); aF[2] = LDA(cb3, 2); aF[3] = LDA(cb3, 3);
        if (stb) { stB(sb2, 0, kt1); stB(sb2, 1, kt1); }

        // ---- G2: A-hi frags (4); stage A(t+2)
        aF[4] = LDA(cb3, 4); aF[5] = LDA(cb3, 5); aF[6] = LDA(cb3, 6); aF[7] = LDA(cb3, 7);
        if (sta) { stA(sa3, 0, kt2); stA(sa3, 1, kt2); stA(sa3, 2, kt2); stA(sa3, 3, kt2); }

        // ---- c1: lo x all, once G1 landed (G2's 4 reads may be outstanding)
        wait_lgkm<4>();
        __builtin_amdgcn_s_setprio(1);
#pragma unroll
        for (int mi = 0; mi < 4; ++mi)
#pragma unroll
            for (int nj = 0; nj < 4; ++nj)
                acc[mi][nj] = __builtin_amdgcn_mfma_f32_16x16x32_bf16(aF[mi], bF[nj], acc[mi][nj], 0, 0, 0);
        __builtin_amdgcn_s_setprio(0);

        // ---- c2: hi x all, once everything landed
        wait_lgkm<0>();
        __builtin_amdgcn_s_setprio(1);
#pragma unroll
        for (int mi = 4; mi < 8; ++mi)
#pragma unroll
            for (int nj = 0; nj < 4; ++nj)
                acc[mi][nj] = __builtin_amdgcn_mfma_f32_16x16x32_bf16(aF[mi], bF[nj], acc[mi][nj], 0, 0, 0);
        __builtin_amdgcn_s_setprio(0);

        // ---- tile boundary: counted vmcnt (A(t+2) stays in flight), collective barrier
        if (t + 1 < nt) {
            if (sta) asm volatile("s_waitcnt vmcnt(4)" ::: "memory");
            else     asm volatile("s_waitcnt vmcnt(0)" ::: "memory");
            __builtin_amdgcn_s_barrier();
        }
        cb3 = (cb3 + 1 == 3) ? 0 : cb3 + 1;
    }

    // epilogue: C/D layout (m89): col = lane&15, row = (lane>>4)*4 + reg
    const int crow = (lane >> 4) * 4;
    const int ccol = lane & 15;
#pragma unroll
    for (int nj = 0; nj < 4; ++nj) {
        const int col = n0 + wc * 64 + nj * 16 + ccol;
        const float bv = bias[col];
#pragma unroll
        for (int mi = 0; mi < 8; ++mi) {
#pragma unroll
            for (int rg = 0; rg < 4; ++rg) {
                const int row = m0 + wr * 128 + mi * 16 + crow + rg;
                float v = acc[mi][nj][rg] + bv;
                if (RELU) v = fmaxf(v, 0.0f);
                if (OUT_BF16) {
                    ((unsigned short*)Cout)[(size_t)row * N + col] = f2bf(v);
                } else {
                    ((float*)Cout)[(size_t)row * N + col] = v;
                }
            }
        }
    }
}

extern "C" void kernel_launch(void* const* d_in, const int* in_sizes, int n_in,
                              void* d_out, int out_size, void* d_ws, size_t ws_size,
                              hipStream_t stream) {
    const float* feat0 = (const float*)d_in[0];
    const float* feat1 = (const float*)d_in[1];
    const float* pts0  = (const float*)d_in[2];
    const float* pts1  = (const float*)d_in[3];
    const int*   ids0  = (const int*)d_in[4];
    const int*   ids1  = (const int*)d_in[5];
    const float* W1    = (const float*)d_in[6];
    const float* b1    = (const float*)d_in[7];
    const float* W2    = (const float*)d_in[8];
    const float* b2    = (const float*)d_in[9];
    float* out = (float*)d_out;

    char* ws = (char*)d_ws;
    unsigned short* xw  = (unsigned short*)(ws);
    unsigned short* h   = (unsigned short*)(ws + 58982400);
    unsigned short* w1t = (unsigned short*)(ws + 117964800);
    unsigned short* w2t = (unsigned short*)(ws + 119144448);

    // LDS per block: A ring-3 (3x16KB) + B ring-2 (2x8KB) = 64 KB -> 2 blocks/CU
    const int LDS = 3 * 16384 + 2 * 8192;
    (void)hipFuncSetAttribute((const void*)&gemm_t<true, true>,
                              hipFuncAttributeMaxDynamicSharedMemorySize, LDS);
    (void)hipFuncSetAttribute((const void*)&gemm_t<false, false>,
                              hipFuncAttributeMaxDynamicSharedMemorySize, LDS);

    dim3 tb(32, 32);
    transpose_to_bf16<<<dim3(768 / 32, 768 / 32), tb, 0, stream>>>(W1, w1t, 768, 768);
    transpose_to_bf16<<<dim3(256 / 32, 768 / 32), tb, 0, stream>>>(W2, w2t, 768, 256);

    struct_pack<<<38400, 64, 0, stream>>>(feat0, feat1, pts0, pts1, ids0, ids1, xw);

    // GEMM1: h = relu(x @ W1 + b1)  M=38400, N=768 -> tiles 150m x 6n = 900 wg (q=112, r=4)
    gemm_t<true, true><<<900, 256, LDS, stream>>>(xw, w1t, b1, (void*)h, 768, 768, 6, 112, 4);
    // GEMM2: out = h @ W2 + b2      M=38400, N=256 -> tiles 150m x 2n = 300 wg (q=37, r=4)
    gemm_t<false, false><<<300, 256, LDS, stream>>>(h, w2t, b2, (void*)out, 768, 256, 2, 37, 4);
}